// Round 4
// baseline (266.694 us; speedup 1.0000x reference)
//
#include <hip/hip_runtime.h>

#define IN_F   4096
#define OUT_F  11008
#define BATCH  16
#define CO     16             // output channels per block (4 waves x 4 rows)
#define BLOCK  256
#define SPLITK 8
#define KCHUNK (IN_F / SPLITK)   // 512 k per block == one LDS tile, ONE barrier

typedef int i32x4 __attribute__((ext_vector_type(4)));

// out[b][o] = bias[o]  (pre-init so main kernel can atomicAdd partials)
__global__ __launch_bounds__(BLOCK) void init_out_kernel(
    const float* __restrict__ bias, float* __restrict__ out)
{
    int idx = blockIdx.x * BLOCK + threadIdx.x;
    if (idx < BATCH * OUT_F) {
        int o = idx % OUT_F;
        out[idx] = bias[o];
    }
}

// Block (bx, by): 16 output channels [bx*16..), K-chunk [by*512..).
// Single-barrier structure: issue ALL memory (8 weight dwordx4 per wave +
// x-chunk global_load_lds) up front, ONE __syncthreads (drains everything),
// then pure LDS+FMA compute — no exposed per-iteration vmcnt stalls.
// Wave ty owns rows o0..o0+3; lane tx covers k = {tx*4..tx*4+3} + 256*it.
// acc[64]: (row r, batch b) at r*16+b; in-place folded wave butterfly, then
// one atomicAdd per lane of scale[o]*partial into bias-initialized out.
__global__ __launch_bounds__(BLOCK) void qlin_kernel(
    const float* __restrict__ x,      // [16, 4096]
    const int*   __restrict__ w,      // [11008, 4096] int8 values in int32
    const float* __restrict__ scale,  // [11008]
    float* __restrict__ out)          // [16, 11008], pre-filled with bias
{
    __shared__ float xs[BATCH][KCHUNK];   // 32 KB

    const int tid = threadIdx.x;
    const int tx  = tid & 63;
    const int ty  = tid >> 6;
    const int o0  = blockIdx.x * CO + ty * 4;
    const int kb  = blockIdx.y * KCHUNK;

    const i32x4* __restrict__ wbase = (const i32x4*)(w + (size_t)o0 * IN_F);

    // ---- issue all weight loads first (HBM long pole, stream-once -> nt) ----
    i32x4 wv[2][4];
    #pragma unroll
    for (int it = 0; it < 2; ++it) {
        const size_t kg4 = (size_t)((kb >> 2) + it * 64 + tx);
        #pragma unroll
        for (int r = 0; r < 4; ++r)
            wv[it][r] = __builtin_nontemporal_load(wbase + kg4 + (size_t)r * (IN_F / 4));
    }

    // ---- stage x chunk [16][512] via async global->LDS, 16B/lane ----
    #pragma unroll
    for (int j = 0; j < (BATCH * KCHUNK / 4) / BLOCK; ++j) {
        int f  = tid + j * BLOCK;         // float4 slot in tile
        int b  = f >> 7;                  // / (KCHUNK/4 = 128)
        int kc = f & 127;
        const float* src = x + (size_t)b * IN_F + kb + kc * 4;
        void* dst = (char*)&xs[0][0] + (size_t)f * 16;
        __builtin_amdgcn_global_load_lds(
            (const __attribute__((address_space(1))) void*)src,
            (__attribute__((address_space(3))) void*)dst,
            16, 0, 0);
    }

    __syncthreads();   // the ONLY barrier: drains weights + x tile together

    float acc[64];
    #pragma unroll
    for (int i = 0; i < 64; ++i) acc[i] = 0.f;

    #pragma unroll
    for (int it = 0; it < 2; ++it) {
        const int kl = it * 256 + tx * 4;   // local k (x4 aligned)

        float wf[4][4];
        #pragma unroll
        for (int r = 0; r < 4; ++r)
            #pragma unroll
            for (int e = 0; e < 4; ++e)
                wf[r][e] = (float)wv[it][r][e];

        // batches in chunks of 4 to bound live float4 registers
        #pragma unroll
        for (int bc = 0; bc < 4; ++bc) {
            float4 xv[4];
            #pragma unroll
            for (int bb = 0; bb < 4; ++bb)
                xv[bb] = *(const float4*)&xs[bc * 4 + bb][kl];

            #pragma unroll
            for (int r = 0; r < 4; ++r)
                #pragma unroll
                for (int bb = 0; bb < 4; ++bb) {
                    float a = acc[r * 16 + bc * 4 + bb];
                    a += wf[r][0] * xv[bb].x;
                    a += wf[r][1] * xv[bb].y;
                    a += wf[r][2] * xv[bb].z;
                    a += wf[r][3] * xv[bb].w;
                    acc[r * 16 + bc * 4 + bb] = a;
                }
        }
    }

    // ---- in-place folding butterfly across 64 lanes ----
    // After folding, lane tx holds the full partial for flat index tx = r*16+b.
    #pragma unroll
    for (int wd = 32; wd >= 1; wd >>= 1) {
        const bool upper = (tx & wd) != 0;
        #pragma unroll
        for (int i = 0; i < wd; ++i) {
            float lo = acc[i]      + __shfl_xor(acc[i],      wd);
            float hi = acc[i + wd] + __shfl_xor(acc[i + wd], wd);
            acc[i] = upper ? hi : lo;
        }
    }

    const int o = o0 + (tx >> 4);
    const int b = tx & 15;
    atomicAdd(&out[(size_t)b * OUT_F + o], acc[0] * scale[o]);
}

extern "C" void kernel_launch(void* const* d_in, const int* in_sizes, int n_in,
                              void* d_out, int out_size, void* d_ws, size_t ws_size,
                              hipStream_t stream) {
    const float* x     = (const float*)d_in[0];
    const int*   w     = (const int*)d_in[1];
    const float* scale = (const float*)d_in[2];
    const float* bias  = (const float*)d_in[3];
    float* out = (float*)d_out;

    init_out_kernel<<<(BATCH * OUT_F + BLOCK - 1) / BLOCK, BLOCK, 0, stream>>>(bias, out);

    dim3 grid(OUT_F / CO, SPLITK);   // 688 x 8 = 5504 blocks
    qlin_kernel<<<grid, dim3(BLOCK), 0, stream>>>(x, w, scale, out);
}

// Round 5
// 261.778 us; speedup vs baseline: 1.0188x; 1.0188x over previous
//
#include <hip/hip_runtime.h>

#define IN_F   4096
#define OUT_F  11008
#define BATCH  16
#define BLOCK  256
#define SPLITK 8
#define KCHUNK (IN_F / SPLITK)     // 512 k per block
#define XPAD   8                   // bf16 elems of row padding (breaks bank aliasing)
#define XSTRIDE (KCHUNK + XPAD)    // 520 bf16 per row; 1040 B (16B-aligned)
#define NSTEP  (KCHUNK / 32)       // 16 mfma k-steps per block

typedef short s16x8 __attribute__((ext_vector_type(8)));   // bf16x8 frag (4 VGPRs)
typedef float f32x4 __attribute__((ext_vector_type(4)));   // C/D frag
typedef int   i32x4 __attribute__((ext_vector_type(4)));

// out[b][o] = bias[o]  (pre-init so main kernel can atomicAdd partials)
__global__ __launch_bounds__(BLOCK) void init_out_kernel(
    const float* __restrict__ bias, float* __restrict__ out)
{
    int idx = blockIdx.x * BLOCK + threadIdx.x;
    if (idx < BATCH * OUT_F) {
        int o = idx % OUT_F;
        out[idx] = bias[o];
    }
}

__device__ __forceinline__ unsigned short bf16_trunc_bits(float f) {
    return (unsigned short)(__float_as_uint(f) >> 16);
}

// Block (bx, by): 64 output channels [bx*64..), K-chunk [by*512..).
// Wave wv owns 16 outputs o0 = bx*64 + wv*16. MFMA 16x16x32 bf16:
//   A[m=lane&15][k=quad*8+j]  (x, hi/lo bf16 planes in LDS)
//   B[k=quad*8+j][n=lane&15]  (w row o0+n, 8 consecutive k from global)
//   D[row=quad*4+reg][col=lane&15] -> out[batch=row][o0+col]
// K-reduction happens inside the matrix pipe -> no shuffle butterfly epilogue.
__global__ __launch_bounds__(BLOCK) void qlin_kernel(
    const float* __restrict__ x,      // [16, 4096]
    const int*   __restrict__ w,      // [11008, 4096] int8 values in int32
    const float* __restrict__ scale,  // [11008]
    float* __restrict__ out)          // [16, 11008], pre-filled with bias
{
    __shared__ alignas(16) unsigned short xhi[BATCH * XSTRIDE];  // 16.25 KB
    __shared__ alignas(16) unsigned short xlo[BATCH * XSTRIDE];  // 16.25 KB

    const int tid  = threadIdx.x;
    const int lane = tid & 63;
    const int wv   = tid >> 6;
    const int n    = lane & 15;       // output-within-tile (B), m (A reads)
    const int quad = lane >> 4;
    const int o0   = blockIdx.x * 64 + wv * 16;
    const int kb   = blockIdx.y * KCHUNK;

    // ---- stage x chunk [16][512] as bf16 hi/lo planes (split for accuracy) ----
    // 2048 float4 total; each thread: 8 coalesced float4 reads + 8B/8B LDS writes.
    const float4* __restrict__ xg = (const float4*)x;
    #pragma unroll
    for (int j = 0; j < (BATCH * KCHUNK / 4) / BLOCK; ++j) {
        int f  = tid + j * BLOCK;
        int b  = f >> 7;                   // / (KCHUNK/4 = 128)
        int kc = f & 127;
        float4 v = xg[(size_t)b * (IN_F / 4) + (kb >> 2) + kc];
        ushort4 h, l;
        {
            unsigned u;
            u = __float_as_uint(v.x); h.x = u >> 16;
            l.x = bf16_trunc_bits(v.x - __uint_as_float(u & 0xFFFF0000u));
            u = __float_as_uint(v.y); h.y = u >> 16;
            l.y = bf16_trunc_bits(v.y - __uint_as_float(u & 0xFFFF0000u));
            u = __float_as_uint(v.z); h.z = u >> 16;
            l.z = bf16_trunc_bits(v.z - __uint_as_float(u & 0xFFFF0000u));
            u = __float_as_uint(v.w); h.w = u >> 16;
            l.w = bf16_trunc_bits(v.w - __uint_as_float(u & 0xFFFF0000u));
        }
        *(ushort4*)&xhi[b * XSTRIDE + kc * 4] = h;
        *(ushort4*)&xlo[b * XSTRIDE + kc * 4] = l;
    }
    __syncthreads();

    // ---- MFMA main loop: 16 k-steps, double-buffered weight loads ----
    const int* __restrict__ wrow = w + (size_t)(o0 + n) * IN_F + kb + quad * 8;
    i32x4 wa[2], wb[2];
    wa[0] = *(const i32x4*)(wrow);
    wb[0] = *(const i32x4*)(wrow + 4);

    f32x4 acc = {0.f, 0.f, 0.f, 0.f};

    #pragma unroll
    for (int s = 0; s < NSTEP; ++s) {
        const int cur = s & 1, nxt = cur ^ 1;
        if (s + 1 < NSTEP) {
            wa[nxt] = *(const i32x4*)(wrow + (s + 1) * 32);
            wb[nxt] = *(const i32x4*)(wrow + (s + 1) * 32 + 4);
        }

        // int32 -> bf16 bits (exact: |w| <= 127 fits bf16 mantissa)
        s16x8 bfrag;
        #pragma unroll
        for (int e = 0; e < 4; ++e) {
            bfrag[e]     = (short)bf16_trunc_bits((float)wa[cur][e]);
            bfrag[4 + e] = (short)bf16_trunc_bits((float)wb[cur][e]);
        }

        const int xoff = n * XSTRIDE + s * 32 + quad * 8;
        s16x8 ah = *(const s16x8*)&xhi[xoff];
        s16x8 al = *(const s16x8*)&xlo[xoff];

        acc = __builtin_amdgcn_mfma_f32_16x16x32_bf16(ah, bfrag, acc, 0, 0, 0);
        acc = __builtin_amdgcn_mfma_f32_16x16x32_bf16(al, bfrag, acc, 0, 0, 0);
    }

    // ---- epilogue: D[row=quad*4+r][col=n] -> atomicAdd into bias-filled out ----
    const int   o  = o0 + n;
    const float sc = scale[o];
    #pragma unroll
    for (int r = 0; r < 4; ++r) {
        const int b = quad * 4 + r;
        atomicAdd(&out[(size_t)b * OUT_F + o], acc[r] * sc);
    }
}

extern "C" void kernel_launch(void* const* d_in, const int* in_sizes, int n_in,
                              void* d_out, int out_size, void* d_ws, size_t ws_size,
                              hipStream_t stream) {
    const float* x     = (const float*)d_in[0];
    const int*   w     = (const int*)d_in[1];
    const float* scale = (const float*)d_in[2];
    const float* bias  = (const float*)d_in[3];
    float* out = (float*)d_out;

    init_out_kernel<<<(BATCH * OUT_F + BLOCK - 1) / BLOCK, BLOCK, 0, stream>>>(bias, out);

    dim3 grid(OUT_F / 64, SPLITK);   // 172 x 8 = 1376 blocks
    qlin_kernel<<<grid, dim3(BLOCK), 0, stream>>>(x, w, scale, out);
}